// Round 12
// baseline (797.777 us; speedup 1.0000x reference)
//
#include <hip/hip_runtime.h>
#include <hip/hip_bf16.h>

#define N_ROWS 4096
#define H_DIM  512
#define V_DIM  50257
#define BM 128
#define BN 128
#define BK 64
#define NSTEP 8
#define VT_TOTAL 393            // ceil(V/BN)
#define V_PAD (VT_TOTAL * BN)   // 50304
#define NCHUNK 131              // 393 = 3*131 -> every block exactly 3 tiles
#define LOG2E 1.4426950408889634f
#define LBASE 65536             // persistent L tile (bf16, 32 KB)
#define SMEM_BYTES 98304

#define LGKM0()  asm volatile("s_waitcnt lgkmcnt(0)" ::: "memory")
#define BARRIER() __builtin_amdgcn_s_barrier()

typedef __attribute__((ext_vector_type(8))) short short8;
typedef __attribute__((ext_vector_type(4))) float f32x4;

template <int N>
static __device__ __forceinline__ void vmw() {
  if constexpr (N == 0)      asm volatile("s_waitcnt vmcnt(0)" ::: "memory");
  else if constexpr (N == 1) asm volatile("s_waitcnt vmcnt(1)" ::: "memory");
  else if constexpr (N == 4) asm volatile("s_waitcnt vmcnt(4)" ::: "memory");
  else                       asm volatile("s_waitcnt vmcnt(5)" ::: "memory");
}

static __device__ __forceinline__ unsigned short f2bf(float f) {
  unsigned u = __float_as_uint(f);
  u = (u + 0x7fffu + ((u >> 16) & 1u)) >> 16;   // RNE
  return (unsigned short)u;
}

static __device__ __forceinline__ void gload_lds16(const void* g, void* l) {
  __builtin_amdgcn_global_load_lds(
      (const __attribute__((address_space(1))) void*)g,
      (__attribute__((address_space(3))) void*)l, 16, 0, 0);
}

// ---------------- kernel A: fp32 -> bf16 conversion (W padded to V_PAD) ----
__global__ void convert_kernel(const float* __restrict__ X,
                               const float* __restrict__ W,
                               __hip_bfloat16* __restrict__ Xb,
                               __hip_bfloat16* __restrict__ Wb) {
  const long wtot8 = (long)V_PAD * H_DIM / 8;
  const long xtot8 = (long)N_ROWS * H_DIM / 8;
  long i = (long)blockIdx.x * blockDim.x + threadIdx.x;
  unsigned short o[8];
  if (i < wtot8) {
    long base = i * 8;
    long row = base >> 9;
    if (row < V_DIM) {
      const float4* s = (const float4*)(W + base);
      float4 a = s[0], b = s[1];
      o[0]=f2bf(a.x); o[1]=f2bf(a.y); o[2]=f2bf(a.z); o[3]=f2bf(a.w);
      o[4]=f2bf(b.x); o[5]=f2bf(b.y); o[6]=f2bf(b.z); o[7]=f2bf(b.w);
    } else {
      #pragma unroll
      for (int k = 0; k < 8; ++k) o[k] = 0;
    }
    *(short8*)(Wb + base) = *(const short8*)o;
  } else if (i < wtot8 + xtot8) {
    long base = (i - wtot8) * 8;
    const float4* s = (const float4*)(X + base);
    float4 a = s[0], b = s[1];
    o[0]=f2bf(a.x); o[1]=f2bf(a.y); o[2]=f2bf(a.z); o[3]=f2bf(a.w);
    o[4]=f2bf(b.x); o[5]=f2bf(b.y); o[6]=f2bf(b.z); o[7]=f2bf(b.w);
    *(short8*)(Xb + base) = *(const short8*)o;
  }
}

// stats for one 4-col chunk; L from packed bf16 uint2 (bias included)
static __device__ __forceinline__ void stats4(
    const f32x4& T, uint2 lw, int gcol0,
    float& ml, float& sl, float& mt, float& st, float& dd) {
  float Lv[4], Tv[4];
  unsigned lu[2] = {lw.x, lw.y};
  #pragma unroll
  for (int j = 0; j < 4; ++j) {
    unsigned h = (lu[j >> 1] >> ((j & 1) * 16)) & 0xffffu;
    float lvf = __uint_as_float(h << 16);
    bool ok = (gcol0 + j < V_DIM);
    Lv[j] = ok ? lvf : -1e30f;
    Tv[j] = ok ? T[j] : -1e30f;
  }
  float g = fmaxf(fmaxf(Lv[0], Lv[1]), fmaxf(Lv[2], Lv[3]));
  if (g > ml + 12.f) { sl *= exp2f((ml - g) * LOG2E); ml = g; }
  float bl = ml * LOG2E;
  sl += exp2f(__builtin_fmaf(Lv[0], LOG2E, -bl))
      + exp2f(__builtin_fmaf(Lv[1], LOG2E, -bl))
      + exp2f(__builtin_fmaf(Lv[2], LOG2E, -bl))
      + exp2f(__builtin_fmaf(Lv[3], LOG2E, -bl));
  float gt = fmaxf(fmaxf(Tv[0], Tv[1]), fmaxf(Tv[2], Tv[3]));
  if (gt > mt + 12.f) {
    float sc = exp2f((mt - gt) * LOG2E);
    st *= sc; dd *= sc; mt = gt;
  }
  float bt = mt * LOG2E;
  #pragma unroll
  for (int j = 0; j < 4; ++j) {
    float e = exp2f(__builtin_fmaf(Tv[j], LOG2E, -bt));
    st += e;
    dd = __builtin_fmaf(e, Lv[j], dd);
  }
}

// ---------------- kernel B: fused GEMM + cross-tile-pipelined stats -------
// Grid (32, 131). Block 512 = 8 waves (2x4 over 128x128 tile), 1 block/CU,
// 96 KB dynamic LDS: 2x32 KB staging dbuf + 32 KB persistent bf16 L tile.
// Stream of tile g-1 runs INSIDE the K-loop of tile g (1 T-float4 + 4-col
// stats per K-step per thread); counted vmcnt(5) keeps loads in flight.
__global__ __launch_bounds__(512, 2)
void fused_kernel(const __hip_bfloat16* __restrict__ Xb,
                  const __hip_bfloat16* __restrict__ Wb,
                  const float* __restrict__ bias,
                  const float* __restrict__ targets,
                  float* __restrict__ partials) {
  extern __shared__ __align__(16) char smem[];

  const int tid  = threadIdx.x;
  const int lane = tid & 63;
  const int wid  = tid >> 6;
  const int wm   = wid >> 2;          // 0..1: 64 x-rows
  const int wn   = wid & 3;           // 0..3: 32 vocab cols
  const int q    = lane >> 4;
  const int c15  = lane & 15;
  const int brow = blockIdx.x;
  const int chunk = blockIdx.y;

  float ml = -1e30f, sl = 0.f, mt = -1e30f, st = 0.f, dd = 0.f;

  // staging: thread t -> site i rows i*64+(t>>3), 16B-unit t&7; source
  // pre-swizzled so swizzled ds_read reads linear fragments (verified r10)
  const int srow8 = tid >> 3;                               // 0..63
  const int soff  = ((tid & 7) ^ (srow8 & 7)) * 8;
  const __hip_bfloat16* asrc = Xb + (long)(brow * BM + srow8) * H_DIM + soff;
  const __hip_bfloat16* wb0  = Wb + (long)((long)chunk * BN + srow8) * H_DIM + soff;
  const long WSTRIDE = (long)NCHUNK * BN * H_DIM;

  // fragment-read precompute (verified round 10)
  const int rm     = (c15 & 7) << 4;
  const int arow_b = (wm * 64 + c15) * 128;
  const int brow_b = (wn * 32 + c15) * 128;

  auto stage = [&](int bufb, const __hip_bfloat16* wsrcp, int kk) {
    #pragma unroll
    for (int i = 0; i < 2; ++i)
      gload_lds16(asrc + (long)i * 64 * H_DIM + kk,
                  smem + bufb + i * 8192 + tid * 16);
    #pragma unroll
    for (int i = 0; i < 2; ++i)
      gload_lds16(wsrcp + (long)i * 64 * H_DIM + kk,
                  smem + bufb + 16384 + i * 8192 + tid * 16);
  };

  // stream precompute: thread owns (row strow, quarter of 32 cols)
  const int strow = tid >> 2;                  // 0..127
  const int quart = tid & 3;
  const int scol  = quart * 32;
  const long grow   = (long)(brow * BM + strow);
  const long growVD = grow * V_DIM;
  const long tlim   = (long)N_ROWS * V_DIM - 4;
  const char* Lrow  = smem + LBASE + strow * 256;
  const int rsw     = (strow & 7) << 4;

  // bias preload for all 3 tiles (static indices)
  f32x4 bp[3][2];
  #pragma unroll
  for (int g = 0; g < 3; ++g) {
    const int v0g = (chunk + g * NCHUNK) * BN + wn * 32 + q * 4;
    #pragma unroll
    for (int b = 0; b < 2; ++b) {
      int bo = v0g + b * 16;
      bo = bo > (V_DIM - 4) ? (V_DIM - 4) : bo;
      bp[g][b] = *(const f32x4*)(bias + bo);
    }
  }

  f32x4 tbuf[2];
  auto loadT = [&](f32x4& dst, int g, int c) {
    long off = growVD + (long)(chunk + g * NCHUNK) * BN + scol + c * 4;
    off = off > tlim ? tlim : off;
    dst = *(const f32x4*)(targets + off);
  };

  // prologue: stage tile0 k0 into buf0
  stage(0, wb0, 0);

  #pragma unroll
  for (int g = 0; g < 3; ++g) {
    const __hip_bfloat16* wcur = wb0 + (long)g * WSTRIDE;
    const int gcPrev = (chunk + (g - 1) * NCHUNK) * BN + scol;  // g>0 only

    f32x4 acc[4][2];
    #pragma unroll
    for (int a = 0; a < 4; ++a)
      #pragma unroll
      for (int b = 0; b < 2; ++b)
        acc[a][b] = (f32x4){0.f, 0.f, 0.f, 0.f};

    #pragma unroll
    for (int ks = 0; ks < NSTEP; ++ks) {
      const int cb = (ks & 1) ? 32768 : 0;
      const int nb = cb ^ 32768;
      if (ks < NSTEP - 1)
        stage(nb, wcur, (ks + 1) * BK);
      else if (g < 2)
        stage(nb, wcur + WSTRIDE, 0);          // next tile k0
      // one T issue per step: chunks of tile g-1 (steps 0..6), chunk0 of
      // tile g at step 7 (feeds the next K-loop / drain)
      if (g > 0 && ks < NSTEP - 1) loadT(tbuf[(ks + 1) & 1], g - 1, ks + 1);
      if (ks == NSTEP - 1)         loadT(tbuf[0], g, 0);

      if (ks == NSTEP - 1 && g == 2)      vmw<1>();
      else if (g == 0 && ks < NSTEP - 1)  vmw<4>();
      else                                vmw<5>();
      BARRIER();

      #pragma unroll
      for (int s = 0; s < 2; ++s) {
        short8 xf[4], wf[2];
        #pragma unroll
        for (int a = 0; a < 4; ++a)
          xf[a] = *(const short8*)(smem + cb + arow_b + a * 2048 +
                                   ((s * 64 + q * 16) ^ rm));
        #pragma unroll
        for (int b = 0; b < 2; ++b)
          wf[b] = *(const short8*)(smem + cb + 16384 + brow_b + b * 2048 +
                                   ((s * 64 + q * 16) ^ rm));
        #pragma unroll
        for (int a = 0; a < 4; ++a)
          #pragma unroll
          for (int b = 0; b < 2; ++b)
            acc[a][b] = __builtin_amdgcn_mfma_f32_16x16x32_bf16(
                wf[b], xf[a], acc[a][b], 0, 0, 0);
      }

      if (g > 0) {   // stream stats: tile g-1 chunk ks (T issued last step)
        uint2 lw = *(const uint2*)(Lrow + ((scol * 2 + ks * 8) ^ rsw));
        stats4(tbuf[ks & 1], lw, gcPrev + ks * 4, ml, sl, mt, st, dd);
      }
      LGKM0();
      BARRIER();
    }

    // dump acc + bias -> bf16 L tile (swizzled); acc dies
    #pragma unroll
    for (int a = 0; a < 4; ++a) {
      const int row = wm * 64 + a * 16 + c15;   // row&7 == c15&7
      char* rb = smem + LBASE + row * 256;
      #pragma unroll
      for (int b = 0; b < 2; ++b) {
        uint2 w;
        w.x = (unsigned)f2bf(acc[a][b][0] + bp[g][b][0]) |
              ((unsigned)f2bf(acc[a][b][1] + bp[g][b][1]) << 16);
        w.y = (unsigned)f2bf(acc[a][b][2] + bp[g][b][2]) |
              ((unsigned)f2bf(acc[a][b][3] + bp[g][b][3]) << 16);
        const int o = wn * 64 + b * 32 + q * 8;
        *(uint2*)(rb + (o ^ rm)) = w;
      }
    }
    LGKM0();
    BARRIER();
  }

  // drain: stream tile 2 (T chunk0 already in flight from K(2) s7)
  const int gcT2 = (chunk + 2 * NCHUNK) * BN + scol;
  #pragma unroll
  for (int c = 0; c < 8; ++c) {
    if (c < 7) loadT(tbuf[(c + 1) & 1], 2, c + 1);
    if (c < 7) vmw<1>(); else vmw<0>();
    uint2 lw = *(const uint2*)(Lrow + ((scol * 2 + c * 8) ^ rsw));
    stats4(tbuf[c & 1], lw, gcT2 + c * 4, ml, sl, mt, st, dd);
  }

  // merge the 4 quarters of each row (lane bits 0,1)
  #pragma unroll
  for (int off = 1; off <= 2; off <<= 1) {
    float ml2 = __shfl_xor(ml, off), sl2 = __shfl_xor(sl, off);
    float mt2 = __shfl_xor(mt, off), st2 = __shfl_xor(st, off);
    float dd2 = __shfl_xor(dd, off);
    float nm = fmaxf(ml, ml2);
    sl = sl * exp2f((ml - nm) * LOG2E) + sl2 * exp2f((ml2 - nm) * LOG2E);
    ml = nm;
    float nmt = fmaxf(mt, mt2);
    float e1 = exp2f((mt - nmt) * LOG2E), e2 = exp2f((mt2 - nmt) * LOG2E);
    st = st * e1 + st2 * e2;
    dd = dd * e1 + dd2 * e2;
    mt = nmt;
  }
  if (quart == 0) {
    float* o = partials + (grow * NCHUNK + chunk) * 5;
    o[0] = ml; o[1] = sl; o[2] = mt; o[3] = st; o[4] = dd;
  }
}

// ---------------- kernel C: merge partials -> per-row loss ----------------
__global__ void rowloss_kernel(const float* __restrict__ partials,
                               float* __restrict__ rowloss) {
  int r = blockIdx.x * blockDim.x + threadIdx.x;
  if (r >= N_ROWS) return;
  const float* p = partials + (long)r * NCHUNK * 5;
  float ml = -1e30f, sl = 0.f, mt = -1e30f, st = 0.f, dd = 0.f;
  for (int c = 0; c < NCHUNK; ++c) {
    float ml2 = p[0], sl2 = p[1], mt2 = p[2], st2 = p[3], dd2 = p[4];
    p += 5;
    float nm = fmaxf(ml, ml2);
    sl = sl * exp2f((ml - nm) * LOG2E) + sl2 * exp2f((ml2 - nm) * LOG2E);
    ml = nm;
    float nmt = fmaxf(mt, mt2);
    float e1 = exp2f((mt - nmt) * LOG2E);
    float e2 = exp2f((mt2 - nmt) * LOG2E);
    st = st * e1 + st2 * e2;
    dd = dd * e1 + dd2 * e2;
    mt = nmt;
  }
  float lse = ml + logf(sl);
  rowloss[r] = lse - dd / st;
}

// ---------------- kernel D: final scalar reduce ---------------------------
__global__ void final_kernel(const float* __restrict__ rowloss,
                             float* __restrict__ out) {
  __shared__ float sm[4];
  float s = 0.f;
  for (int i = threadIdx.x; i < N_ROWS; i += 256) s += rowloss[i];
  #pragma unroll
  for (int off = 32; off > 0; off >>= 1) s += __shfl_down(s, off);
  if ((threadIdx.x & 63) == 0) sm[threadIdx.x >> 6] = s;
  __syncthreads();
  if (threadIdx.x == 0) out[0] = (sm[0] + sm[1] + sm[2] + sm[3]) * (1.0f / (float)N_ROWS);
}

extern "C" void kernel_launch(void* const* d_in, const int* in_sizes, int n_in,
                              void* d_out, int out_size, void* d_ws, size_t ws_size,
                              hipStream_t stream) {
  const float* x       = (const float*)d_in[0];   // [4096, 512]
  const float* targets = (const float*)d_in[1];   // [4096, 50257]
  const float* weight  = (const float*)d_in[2];   // [50257, 512]
  const float* bias    = (const float*)d_in[3];   // [50257]
  float* out = (float*)d_out;

  char* ws = (char*)d_ws;
  __hip_bfloat16* Wb = (__hip_bfloat16*)ws;                     // 51,511,296 B
  size_t off = (size_t)V_PAD * H_DIM * 2;
  __hip_bfloat16* Xb = (__hip_bfloat16*)(ws + off);             //  4,194,304 B
  off += (size_t)N_ROWS * H_DIM * 2;
  float* partials = (float*)(ws + off);                         // 10,731,520 B
  off += (size_t)N_ROWS * NCHUNK * 5 * sizeof(float);
  float* rowloss = (float*)(ws + off);                          //     16,384 B

  (void)hipFuncSetAttribute((const void*)fused_kernel,
                            hipFuncAttributeMaxDynamicSharedMemorySize,
                            SMEM_BYTES);

  convert_kernel<<<13600, 256, 0, stream>>>(x, weight, Xb, Wb);
  dim3 grid(N_ROWS / BM, NCHUNK);
  fused_kernel<<<grid, 512, SMEM_BYTES, stream>>>(Xb, Wb, bias, targets, partials);
  rowloss_kernel<<<N_ROWS / 256, 256, 0, stream>>>(partials, rowloss);
  final_kernel<<<1, 256, 0, stream>>>(rowloss, out);
}

// Round 13
// 605.273 us; speedup vs baseline: 1.3180x; 1.3180x over previous
//
#include <hip/hip_runtime.h>
#include <hip/hip_bf16.h>

#define N_ROWS 4096
#define H_DIM  512
#define V_DIM  50257
#define BM 256
#define BN 256
#define BK 64
#define NSTEP 8                 // 512 / 64
#define VCH 197                 // ceil(V/256)
#define V_PAD (VCH * 256)       // 50432
#define LOG2E 1.4426950408889634f
#define BUFSZ 65536             // one staging buf: A 32K + B 32K
#define SMEM_BYTES 131072

#define LGKM0()  asm volatile("s_waitcnt lgkmcnt(0)" ::: "memory")
#define BARRIER() __builtin_amdgcn_s_barrier()

typedef __attribute__((ext_vector_type(8))) short short8;
typedef __attribute__((ext_vector_type(4))) float f32x4;

template <int N>
static __device__ __forceinline__ void vmw() {
  if constexpr (N == 0)      asm volatile("s_waitcnt vmcnt(0)" ::: "memory");
  else                       asm volatile("s_waitcnt vmcnt(8)" ::: "memory");
}

static __device__ __forceinline__ unsigned short f2bf(float f) {
  unsigned u = __float_as_uint(f);
  u = (u + 0x7fffu + ((u >> 16) & 1u)) >> 16;   // RNE
  return (unsigned short)u;
}

static __device__ __forceinline__ void gload_lds16(const void* g, void* l) {
  __builtin_amdgcn_global_load_lds(
      (const __attribute__((address_space(1))) void*)g,
      (__attribute__((address_space(3))) void*)l, 16, 0, 0);
}

// ---------------- kernel A: fp32 -> bf16 conversion (W padded to V_PAD) ----
__global__ void convert_kernel(const float* __restrict__ X,
                               const float* __restrict__ W,
                               __hip_bfloat16* __restrict__ Xb,
                               __hip_bfloat16* __restrict__ Wb) {
  const long wtot8 = (long)V_PAD * H_DIM / 8;   // 3,227,648
  const long xtot8 = (long)N_ROWS * H_DIM / 8;  //   262,144
  long i = (long)blockIdx.x * blockDim.x + threadIdx.x;
  unsigned short o[8];
  if (i < wtot8) {
    long base = i * 8;
    long row = base >> 9;
    if (row < V_DIM) {
      const float4* s = (const float4*)(W + base);
      float4 a = s[0], b = s[1];
      o[0]=f2bf(a.x); o[1]=f2bf(a.y); o[2]=f2bf(a.z); o[3]=f2bf(a.w);
      o[4]=f2bf(b.x); o[5]=f2bf(b.y); o[6]=f2bf(b.z); o[7]=f2bf(b.w);
    } else {
      #pragma unroll
      for (int k = 0; k < 8; ++k) o[k] = 0;
    }
    *(short8*)(Wb + base) = *(const short8*)o;
  } else if (i < wtot8 + xtot8) {
    long base = (i - wtot8) * 8;
    const float4* s = (const float4*)(X + base);
    float4 a = s[0], b = s[1];
    o[0]=f2bf(a.x); o[1]=f2bf(a.y); o[2]=f2bf(a.z); o[3]=f2bf(a.w);
    o[4]=f2bf(b.x); o[5]=f2bf(b.y); o[6]=f2bf(b.z); o[7]=f2bf(b.w);
    *(short8*)(Xb + base) = *(const short8*)o;
  }
}

// stats update for one 16-col chunk (Lraw includes bias)
template <bool GUARD>
static __device__ __forceinline__ void stats16(
    const float (&Lraw)[16], const f32x4* T4, int gcol0,
    float& ml, float& sl, float& mt, float& st, float& dd) {
  float Lv[16], Tv[16];
  #pragma unroll
  for (int k = 0; k < 16; ++k) {
    const bool ok = !GUARD || (gcol0 + k < V_DIM);
    Lv[k] = ok ? Lraw[k] : -1e30f;
    Tv[k] = ok ? T4[k >> 2][k & 3] : -1e30f;
  }
  float g = Lv[0];
  #pragma unroll
  for (int k = 1; k < 16; ++k) g = fmaxf(g, Lv[k]);
  if (g > ml + 12.f) { sl *= exp2f((ml - g) * LOG2E); ml = g; }
  float bl = ml * LOG2E;
  float ss = 0.f;
  #pragma unroll
  for (int k = 0; k < 16; ++k) ss += exp2f(__builtin_fmaf(Lv[k], LOG2E, -bl));
  sl += ss;
  float gt = Tv[0];
  #pragma unroll
  for (int k = 1; k < 16; ++k) gt = fmaxf(gt, Tv[k]);
  if (gt > mt + 12.f) {
    float sc = exp2f((mt - gt) * LOG2E);
    st *= sc; dd *= sc; mt = gt;
  }
  float bt = mt * LOG2E;
  float s2 = 0.f, d2 = 0.f;
  #pragma unroll
  for (int k = 0; k < 16; ++k) {
    float e = exp2f(__builtin_fmaf(Tv[k], LOG2E, -bt));
    s2 += e;
    d2 = __builtin_fmaf(e, Lv[k], d2);
  }
  st += s2; dd += d2;
}

// stream one 64-col segment (4 chunks of 16), 2-deep T pipeline.
// L is bf16 in LDS at Lrow (256 B rows, XOR-swizzled by (row&7)<<4).
template <bool GUARD>
static __device__ __forceinline__ void stream_seg(
    const float* __restrict__ targets, const char* __restrict__ Lrow,
    long tbase, int gcol0, int lbyte0, int rsw, long tlim,
    float& ml, float& sl, float& mt, float& st, float& dd) {
  f32x4 T0[4], T1[4];
  auto LOADT = [&](f32x4 (&D)[4], int i) {
    #pragma unroll
    for (int c = 0; c < 4; ++c) {
      long off = tbase + i * 16 + c * 4;
      if (GUARD) off = off > tlim ? tlim : off;
      D[c] = *(const f32x4*)(targets + off);
    }
  };
  auto DOCHUNK = [&](const f32x4 (&T)[4], int i) {
    const int ob = lbyte0 + (i << 5);
    short8 l0 = *(const short8*)(Lrow + (ob ^ rsw));
    short8 l1 = *(const short8*)(Lrow + ((ob + 16) ^ rsw));
    float Lraw[16];
    #pragma unroll
    for (int e = 0; e < 8; ++e) {
      Lraw[e]     = __uint_as_float(((unsigned)(unsigned short)l0[e]) << 16);
      Lraw[e + 8] = __uint_as_float(((unsigned)(unsigned short)l1[e]) << 16);
    }
    stats16<GUARD>(Lraw, T, gcol0 + i * 16, ml, sl, mt, st, dd);
  };
  LOADT(T0, 0); LOADT(T1, 1);
  DOCHUNK(T0, 0);
  LOADT(T0, 2);
  DOCHUNK(T1, 1);
  LOADT(T1, 3);
  DOCHUNK(T0, 2);
  DOCHUNK(T1, 3);
}

// ---------------- kernel B: fused 256x256 GEMM + online softmax stats -----
// Grid (16, 197). Block 512 = 8 waves (2M x 4N; 128x64 per wave). BK=64,
// double-buffered staging (2 x 64 KB), counted vmcnt(8). After the K-loop
// buf0 is dead: bf16 L tile (256x128 half) lives there; dump+stream twice.
__global__ __launch_bounds__(512, 2)
void fused_kernel(const __hip_bfloat16* __restrict__ Xb,
                  const __hip_bfloat16* __restrict__ Wb,
                  const float* __restrict__ bias,
                  const float* __restrict__ targets,
                  float* __restrict__ partials) {
  extern __shared__ __align__(16) char smem[];   // 2 x {A 32K | B 32K}

  const int tid  = threadIdx.x;
  const int lane = tid & 63;
  const int wid  = tid >> 6;
  const int wm   = wid >> 2;          // 0..1 : rows wm*128..+128
  const int wn   = wid & 3;           // 0..3 : cols wn*64..+64
  const int q    = lane >> 4;
  const int c15  = lane & 15;
  const int brow = blockIdx.x;
  const int vchunk = blockIdx.y;
  const int vbase = vchunk * BN;

  float ml = -1e30f, sl = 0.f, mt = -1e30f, st = 0.f, dd = 0.f;

  // staging: thread t covers row (t>>3) (+64 per issue), 16B-unit t&7;
  // global source pre-swizzled so swizzled ds_read is conflict-free (r8).
  const int srow8 = tid >> 3;                               // 0..63
  const int soff  = ((tid & 7) ^ (srow8 & 7)) * 8;
  const __hip_bfloat16* asrc = Xb + (long)(brow * BM + srow8) * H_DIM + soff;
  const __hip_bfloat16* wsrc = Wb + (long)(vbase + srow8) * H_DIM + soff;

  // fragment-read precompute (round-8 verbatim, 128 B rows)
  const int rm     = (c15 & 7) << 4;
  const int arow_b = (wm * 128 + c15) * 128;   // + a*2048
  const int brow_b = (wn * 64 + c15) * 128;    // + b*2048 (+32768 B-region)

  auto stage = [&](int bufb, int kk) {
    #pragma unroll
    for (int i = 0; i < 4; ++i)
      gload_lds16(asrc + (long)i * 64 * H_DIM + kk,
                  smem + bufb + i * 8192 + tid * 16);
    #pragma unroll
    for (int i = 0; i < 4; ++i)
      gload_lds16(wsrc + (long)i * 64 * H_DIM + kk,
                  smem + bufb + 32768 + i * 8192 + tid * 16);
  };

  // prologue: stage k0 into buf0
  stage(0, 0);

  f32x4 acc[8][4];
  #pragma unroll
  for (int a = 0; a < 8; ++a)
    #pragma unroll
    for (int b = 0; b < 4; ++b)
      acc[a][b] = (f32x4){0.f, 0.f, 0.f, 0.f};

  // ---- pipelined K-loop: counted vmcnt, raw barriers ----
  #pragma unroll
  for (int ks = 0; ks < NSTEP; ++ks) {
    const int cb = (ks & 1) ? BUFSZ : 0;
    if (ks < NSTEP - 1) stage(cb ^ BUFSZ, (ks + 1) * BK);

    if (ks == NSTEP - 1) vmw<0>(); else vmw<8>();
    BARRIER();

    #pragma unroll
    for (int s = 0; s < 2; ++s) {
      short8 xf[8], wf[4];
      #pragma unroll
      for (int a = 0; a < 8; ++a)
        xf[a] = *(const short8*)(smem + cb + arow_b + a * 2048 +
                                 ((s * 64 + q * 16) ^ rm));
      #pragma unroll
      for (int b = 0; b < 4; ++b)
        wf[b] = *(const short8*)(smem + cb + 32768 + brow_b + b * 2048 +
                                 ((s * 64 + q * 16) ^ rm));
      #pragma unroll
      for (int a = 0; a < 8; ++a)
        #pragma unroll
        for (int b = 0; b < 4; ++b)
          acc[a][b] = __builtin_amdgcn_mfma_f32_16x16x32_bf16(
              wf[b], xf[a], acc[a][b], 0, 0, 0);
    }
    LGKM0();
    BARRIER();
  }

  // ---- bias for this wave's 64 cols ----
  f32x4 bp[4];
  {
    const int v0 = vbase + wn * 64 + q * 4;
    #pragma unroll
    for (int b = 0; b < 4; ++b) {
      int bo = v0 + b * 16;
      bo = bo > (V_DIM - 4) ? (V_DIM - 4) : bo;
      bp[b] = *(const f32x4*)(bias + bo);
    }
  }

  // stream precompute: thread owns (row = tid>>1, 64-col segment = tid&1)
  const int srow  = tid >> 1;                  // 0..255
  const int seg   = tid & 1;
  const long grow = (long)(brow * BM + srow);
  const long tlim = (long)N_ROWS * V_DIM - 4;
  const char* Lrow = smem + srow * 256;        // L on buf0 region
  const int rsw    = (srow & 7) << 4;
  const int lbyte0 = seg * 128;
  const bool guard = (vbase + BN > V_DIM);

  // ---- two halves: dump (acc+bias -> bf16 L, swizzled) then stream ----
  #pragma unroll
  for (int h = 0; h < 2; ++h) {
    if ((wn >> 1) == h) {
      #pragma unroll
      for (int a = 0; a < 8; ++a) {
        const int row = wm * 128 + a * 16 + c15;   // row&7 == c15&7
        char* rb = smem + row * 256;
        #pragma unroll
        for (int b = 0; b < 4; ++b) {
          uint2 w;
          w.x = (unsigned)f2bf(acc[a][b][0] + bp[b][0]) |
                ((unsigned)f2bf(acc[a][b][1] + bp[b][1]) << 16);
          w.y = (unsigned)f2bf(acc[a][b][2] + bp[b][2]) |
                ((unsigned)f2bf(acc[a][b][3] + bp[b][3]) << 16);
          const int o = (wn & 1) * 128 + b * 32 + q * 8;
          *(uint2*)(rb + (o ^ rm)) = w;
        }
      }
    }
    LGKM0();
    BARRIER();

    const int gcol0 = vbase + h * 128 + seg * 64;
    const long tbase = grow * V_DIM + gcol0;
    if (guard)
      stream_seg<true >(targets, Lrow, tbase, gcol0, lbyte0, rsw, tlim,
                        ml, sl, mt, st, dd);
    else
      stream_seg<false>(targets, Lrow, tbase, gcol0, lbyte0, rsw, tlim,
                        ml, sl, mt, st, dd);
    BARRIER();   // all L reads consumed before next dump overwrites
  }

  // merge the two segments of each row (lane bit 0)
  {
    float ml2 = __shfl_xor(ml, 1), sl2 = __shfl_xor(sl, 1);
    float mt2 = __shfl_xor(mt, 1), st2 = __shfl_xor(st, 1);
    float dd2 = __shfl_xor(dd, 1);
    float nm = fmaxf(ml, ml2);
    float slo = sl * exp2f((ml - nm) * LOG2E) + sl2 * exp2f((ml2 - nm) * LOG2E);
    float nmt = fmaxf(mt, mt2);
    float e1 = exp2f((mt - nmt) * LOG2E), e2 = exp2f((mt2 - nmt) * LOG2E);
    float sto = st * e1 + st2 * e2;
    float ddo = dd * e1 + dd2 * e2;
    if (seg == 0) {
      float* o = partials + (grow * VCH + vchunk) * 5;
      o[0] = nm; o[1] = slo; o[2] = nmt; o[3] = sto; o[4] = ddo;
    }
  }
}

// ---------------- kernel C: merge partials -> per-row loss ----------------
__global__ void rowloss_kernel(const float* __restrict__ partials,
                               float* __restrict__ rowloss) {
  int r = blockIdx.x * blockDim.x + threadIdx.x;
  if (r >= N_ROWS) return;
  const float* p = partials + (long)r * VCH * 5;
  float ml = -1e30f, sl = 0.f, mt = -1e30f, st = 0.f, dd = 0.f;
  for (int c = 0; c < VCH; ++c) {
    float ml2 = p[0], sl2 = p[1], mt2 = p[2], st2 = p[3], dd2 = p[4];
    p += 5;
    float nm = fmaxf(ml, ml2);
    sl = sl * exp2f((ml - nm) * LOG2E) + sl2 * exp2f((ml2 - nm) * LOG2E);
    ml = nm;
    float nmt = fmaxf(mt, mt2);
    float e1 = exp2f((mt - nmt) * LOG2E);
    float e2 = exp2f((mt2 - nmt) * LOG2E);
    st = st * e1 + st2 * e2;
    dd = dd * e1 + dd2 * e2;
    mt = nmt;
  }
  float lse = ml + logf(sl);
  rowloss[r] = lse - dd / st;
}

// ---------------- kernel D: final scalar reduce ---------------------------
__global__ void final_kernel(const float* __restrict__ rowloss,
                             float* __restrict__ out) {
  __shared__ float sm[4];
  float s = 0.f;
  for (int i = threadIdx.x; i < N_ROWS; i += 256) s += rowloss[i];
  #pragma unroll
  for (int off = 32; off > 0; off >>= 1) s += __shfl_down(s, off);
  if ((threadIdx.x & 63) == 0) sm[threadIdx.x >> 6] = s;
  __syncthreads();
  if (threadIdx.x == 0) out[0] = (sm[0] + sm[1] + sm[2] + sm[3]) * (1.0f / (float)N_ROWS);
}

extern "C" void kernel_launch(void* const* d_in, const int* in_sizes, int n_in,
                              void* d_out, int out_size, void* d_ws, size_t ws_size,
                              hipStream_t stream) {
  const float* x       = (const float*)d_in[0];   // [4096, 512]
  const float* targets = (const float*)d_in[1];   // [4096, 50257]
  const float* weight  = (const float*)d_in[2];   // [50257, 512]
  const float* bias    = (const float*)d_in[3];   // [50257]
  float* out = (float*)d_out;

  char* ws = (char*)d_ws;
  __hip_bfloat16* Wb = (__hip_bfloat16*)ws;                     // 51,642,368 B
  size_t off = (size_t)V_PAD * H_DIM * 2;
  __hip_bfloat16* Xb = (__hip_bfloat16*)(ws + off);             //  4,194,304 B
  off += (size_t)N_ROWS * H_DIM * 2;
  float* partials = (float*)(ws + off);                         // 16,138,240 B
  off += (size_t)N_ROWS * VCH * 5 * sizeof(float);
  float* rowloss = (float*)(ws + off);                          //     16,384 B

  (void)hipFuncSetAttribute((const void*)fused_kernel,
                            hipFuncAttributeMaxDynamicSharedMemorySize,
                            SMEM_BYTES);

  convert_kernel<<<13632, 256, 0, stream>>>(x, weight, Xb, Wb);
  dim3 grid(N_ROWS / BM, VCH);
  fused_kernel<<<grid, 512, SMEM_BYTES, stream>>>(Xb, Wb, bias, targets, partials);
  rowloss_kernel<<<N_ROWS / 256, 256, 0, stream>>>(partials, rowloss);
  final_kernel<<<1, 256, 0, stream>>>(rowloss, out);
}